// Round 7
// baseline (511.995 us; speedup 1.0000x reference)
//
#include <hip/hip_runtime.h>
#include <hip/hip_bf16.h>

typedef __hip_bfloat16 bf16;
typedef __attribute__((ext_vector_type(8))) short short8;
typedef __attribute__((ext_vector_type(4))) short short4v;
typedef __attribute__((ext_vector_type(4))) float f32x4;

#define CB 2
#define CL 2048
#define CD 1024
#define CH 4096
#define NHEADS 16
#define DH 64

__device__ __forceinline__ short f2bs(float f) {
    __hip_bfloat16 h = __float2bfloat16(f);
    return *reinterpret_cast<short*>(&h);
}
__device__ __forceinline__ float bs2f(short s) {
    __hip_bfloat16 h = *reinterpret_cast<__hip_bfloat16*>(&s);
    return __bfloat162float(h);
}

__device__ __forceinline__ void async_copy16(const short* g, short* l) {
    __builtin_amdgcn_global_load_lds((const __attribute__((address_space(1))) unsigned int*)g,
                                     (__attribute__((address_space(3))) unsigned int*)l,
                                     16, 0, 0);
}

// pack QKV bias + zero LN stats (one launch)
__global__ void pack_bias_kernel(const float* __restrict__ bq, const float* __restrict__ bk,
                                 const float* __restrict__ bv, float* __restrict__ o,
                                 float* __restrict__ stats) {
    int i = blockIdx.x * 256 + threadIdx.x;
    if (i < 16) stats[i] = 0.0f;
    if (i < 3072) o[i] = i < 1024 ? bq[i] : (i < 2048 ? bk[i - 1024] : bv[i - 2048]);
}

// x fp32 -> bf16, 4 elems/thread
__global__ void cvt_x_kernel(const float* __restrict__ x, short* __restrict__ o) {
    const int i = (blockIdx.x * 256 + threadIdx.x) * 4;
    const float4 v = *(const float4*)&x[i];
    short4v s; s[0] = f2bs(v.x); s[1] = f2bs(v.y); s[2] = f2bs(v.z); s[3] = f2bs(v.w);
    *(short4v*)&o[i] = s;
}

// in[K][N] f32 -> out[row_off + n][k] bf16 (out row stride = K)
__global__ void transpose_cvt(const float* __restrict__ in, short* __restrict__ out,
                              int K, int N, int row_off) {
    __shared__ float T[32][33];
    const int tx = threadIdx.x & 31, ty = threadIdx.x >> 5;
    const int k0 = blockIdx.y * 32, n0 = blockIdx.x * 32;
    #pragma unroll
    for (int i = 0; i < 4; ++i)
        T[ty + i * 8][tx] = in[(size_t)(k0 + ty + i * 8) * N + n0 + tx];
    __syncthreads();
    #pragma unroll
    for (int i = 0; i < 4; ++i)
        out[(size_t)(row_off + n0 + ty + i * 8) * K + k0 + tx] = f2bs(T[tx][ty + i * 8]);
}

// 3 QKV weight transposes in one launch (z selects source)
__global__ void transpose_qkv(const float* __restrict__ wq, const float* __restrict__ wk,
                              const float* __restrict__ wv, short* __restrict__ out) {
    __shared__ float T[32][33];
    const int z = blockIdx.z;
    const float* in = z == 0 ? wq : (z == 1 ? wk : wv);
    const int row_off = z * 1024;
    const int tx = threadIdx.x & 31, ty = threadIdx.x >> 5;
    const int k0 = blockIdx.y * 32, n0 = blockIdx.x * 32;
    #pragma unroll
    for (int i = 0; i < 4; ++i)
        T[ty + i * 8][tx] = in[(size_t)(k0 + ty + i * 8) * CD + n0 + tx];
    __syncthreads();
    #pragma unroll
    for (int i = 0; i < 4; ++i)
        out[(size_t)(row_off + n0 + ty + i * 8) * CD + k0 + tx] = f2bs(T[tx][ty + i * 8]);
}

// ---------------------------------------------------------------------------
// MFMA GEMM (R2-exact, last all-pass configuration). BM=128, BN in {128,64},
// BK in {64,128} as BK/32 32-K slabs in LDS, staged chunk-linearly
// (chunk c -> &As[c*8]). Measured model (R2-R5): duration = staged-bytes /
// ~10.7 TB/s at >=2 blocks/CU; schedule variants (DB, counted vmcnt, 8-wave)
// do not change it. Grid must be (N/BN, 32).
// EPI 0: C = act(acc+bias)
// EPI 1: QKV split: col<2048 -> qk[row*2048+col]; col>=2048 -> vT permuted:
//        within each 64-key group, key k -> pos (k5,k3,k2,k4,k1,k0) so attn's
//        PV A-fragment is one contiguous 16B read.
// EPI 2: LN2: v += C(hbuf); in-place write; atomicAdd (sum,sumsq) -> stats
// ---------------------------------------------------------------------------
template <int BN, int BK, int RELU, int EPI>
__launch_bounds__(256)
__global__ void gemm_mfma(const short* __restrict__ A,
                          const short* __restrict__ Bt,
                          const float* __restrict__ bias,
                          short* __restrict__ C,
                          short* __restrict__ C2,
                          int M, int N, int K,
                          float* __restrict__ stats) {
    constexpr int NT = BN / 32;
    constexpr int KH = BK / 32;              // slabs
    constexpr int ACH = 16 * BK;             // A chunks total
    constexpr int BCH = BN * BK / 8;         // B chunks total
    __shared__ short As[128 * BK];           // slab s = chunks [s*512, s*512+512)
    __shared__ short Bs[BN * BK];            // slab s = chunks [s*BN*4, ...)
    __shared__ float red[8];

    const int tid = threadIdx.x;
    const int wave = tid >> 6, lane = tid & 63, quad = lane >> 4, lm = lane & 15;
    const int wm = (wave & 1) * 64, wn = (wave >> 1) * (NT * 16);

    // XCD-aware swizzle (assumes gridDim.y == 32, hw xcd = linear id % 8)
    const int id = blockIdx.y * gridDim.x + blockIdx.x;
    const int xcd = id & 7, within = id >> 3;
    const int by = xcd * 4 + (within & 3);
    const int bx = within >> 2;
    const int row0 = by * 128, col0 = bx * BN;

    f32x4 acc[4][NT];
    #pragma unroll
    for (int i = 0; i < 4; ++i)
        #pragma unroll
        for (int j = 0; j < NT; ++j) { f32x4 z = {0.f, 0.f, 0.f, 0.f}; acc[i][j] = z; }

    for (int k0 = 0; k0 < K; k0 += BK) {
        // A: chunk-linear (slab = 512 chunks of 16B = 128 rows x 32 k)
        #pragma unroll
        for (int t = 0; t < ACH / 256; ++t) {
            const int c = t * 256 + tid;
            const int slab = c >> 9, idx = c & 511;
            const int r = idx >> 2, seg = idx & 3;
            async_copy16(A + (size_t)(row0 + r) * K + k0 + slab * 32 + seg * 8, &As[c * 8]);
        }
        // B: chunk-linear (slab = BN*4 chunks)
        #pragma unroll
        for (int t = 0; t < BCH / 256; ++t) {
            const int c = t * 256 + tid;
            const int slab = c / (BN * 4), idx = c % (BN * 4);
            const int r = idx >> 2, seg = idx & 3;
            async_copy16(Bt + (size_t)(col0 + r) * K + k0 + slab * 32 + seg * 8, &Bs[c * 8]);
        }
        __syncthreads();

        #pragma unroll
        for (int kh = 0; kh < KH; ++kh) {
            short8 af[4], bfr[NT];
            #pragma unroll
            for (int mt = 0; mt < 4; ++mt)
                af[mt] = *(const short8*)&As[kh * 4096 + (wm + mt * 16 + lm) * 32 + quad * 8];
            #pragma unroll
            for (int nt = 0; nt < NT; ++nt)
                bfr[nt] = *(const short8*)&Bs[kh * (BN * 32) + (wn + nt * 16 + lm) * 32 + quad * 8];
            #pragma unroll
            for (int mt = 0; mt < 4; ++mt)
                #pragma unroll
                for (int nt = 0; nt < NT; ++nt)
                    acc[mt][nt] = __builtin_amdgcn_mfma_f32_16x16x32_bf16(af[mt], bfr[nt], acc[mt][nt], 0, 0, 0);
        }
        __syncthreads();
    }

    float s1 = 0.f, s2 = 0.f;
    #pragma unroll
    for (int mt = 0; mt < 4; ++mt) {
        #pragma unroll
        for (int nt = 0; nt < NT; ++nt) {
            const int col = col0 + wn + nt * 16 + lm;
            const float bv = bias[col];
            const int rowb = row0 + wm + mt * 16 + quad * 4;
            if (EPI == 1 && col >= 2048) {
                const int b = row0 >> 11;
                const int l0 = rowb & (CL - 1);
                // key permutation within 64-group: k5,k4,k3,k2 -> c5=k5,
                // c4=k3, c3=k2, c2=k4 (k1k0=0 here; store stays 4-aligned)
                const int lp = (l0 & ~63) | (l0 & 32) | ((l0 & 12) << 1) | ((l0 & 16) >> 2);
                short4v sv;
                #pragma unroll
                for (int r = 0; r < 4; ++r) sv[r] = f2bs(acc[mt][nt][r] + bv);
                *(short4v*)&C2[(size_t)b * CD * CL + (size_t)(col - 2048) * CL + lp] = sv;
            } else {
                #pragma unroll
                for (int r = 0; r < 4; ++r) {
                    float v = acc[mt][nt][r] + bv;
                    if (RELU) v = fmaxf(v, 0.f);
                    const int ld = (EPI == 1) ? 2048 : N;
                    const size_t idx = (size_t)(rowb + r) * ld + col;
                    if (EPI == 2) {
                        v += bs2f(C[idx]);
                        s1 += v; s2 += v * v;
                    }
                    C[idx] = f2bs(v);
                }
            }
        }
    }
    if (EPI == 2) {
        #pragma unroll
        for (int off = 1; off <= 32; off <<= 1) {
            s1 += __shfl_xor(s1, off, 64);
            s2 += __shfl_xor(s2, off, 64);
        }
        if (lane == 0) { red[wave] = s1; red[4 + wave] = s2; }
        __syncthreads();
        if (tid == 0) {
            const int batch = row0 >> 11;
            atomicAdd(&stats[batch * 2 + 0], red[0] + red[1] + red[2] + red[3]);
            atomicAdd(&stats[batch * 2 + 1], red[4] + red[5] + red[6] + red[7]);
        }
    }
}

// ---------------------------------------------------------------------------
// Attention, S^T formulation, KT=64 keys/iter, dense PV.
// R7: NO LDS staging. K/V for one (b,h) = 512 KB, and the XCD swizzle pins
// all 16 q-blocks of a (b,h) to one XCD (8 groups x 512 KB = 4 MB = one L2)
// -> K/V fragments are read DIRECTLY from global (L2-resident), coalesced:
// lanes {quad}x{lm} cover 16 rows x 64B full lines per instruction.
// Removes all loop barriers / vmcnt drains / LDS bank conflicts; 8 fully
// independent waves per block (2 blocks/CU -> 4 waves/SIMD) so one wave's
// exp/cvt VALU stretch overlaps another's MFMA. V is pre-permuted in global
// (gemm EPI 1) so the PV A-fragment is one contiguous 16B read.
// ---------------------------------------------------------------------------
__launch_bounds__(512)
__global__ void attn_mfma(const short* __restrict__ qk,
                          const short* __restrict__ vT,
                          const float* __restrict__ x,
                          short* __restrict__ sbuf,
                          float* __restrict__ stats) {
    __shared__ float red[16];

    const int tid = threadIdx.x;
    const int wave = tid >> 6, lane = tid & 63, quad = lane >> 4, lm = lane & 15;

    const int id = blockIdx.z * (16 * 16) + blockIdx.y * 16 + blockIdx.x;
    const int xcd = id & 7, rest = id >> 3;
    const int qx = rest & 15, gq = rest >> 4;
    const int g = gq * 8 + xcd;
    const int h = g & 15, b = g >> 4;

    const int hoff = h * DH;
    const size_t rowb = (size_t)b * CL;
    const size_t vbase = (size_t)b * CD * CL + (size_t)hoff * CL;
    const int qbase0 = qx * 128 + wave * 16;

    short8 bq[2];
    #pragma unroll
    for (int kf = 0; kf < 2; ++kf)
        bq[kf] = *(const short8*)(qk + (rowb + qbase0 + lm) * 2048 + hoff + kf * 32 + quad * 8);

    f32x4 oacc[4];
    #pragma unroll
    for (int mt = 0; mt < 4; ++mt) { f32x4 z = {0.f, 0.f, 0.f, 0.f}; oacc[mt] = z; }
    float lsum = 0.f;

    // Per-lane fragment base pointers (derived from the R2 LDS-read
    // semantics with the staging XOR-involutions cancelled):
    //   K frag: qk[(rowb + kt*64 + ktile*16 + lm)*2048 + 1024 + hoff + quad*8]
    //   V frag: vT[vbase + (mt*16 + lm)*CL + kt*64 + p*32 + quad*8]
    const short* kbase = qk + (rowb + lm) * 2048 + 1024 + hoff + quad * 8;
    const short* vbp   = vT + vbase + (size_t)lm * CL + quad * 8;

    for (int kt = 0; kt < CL / 64; ++kt) {
        const short* kb = kbase + (size_t)kt * 64 * 2048;
        short8 ka[8];
        #pragma unroll
        for (int ktile = 0; ktile < 4; ++ktile) {
            ka[2 * ktile]     = *(const short8*)(kb + (size_t)ktile * 16 * 2048);
            ka[2 * ktile + 1] = *(const short8*)(kb + (size_t)ktile * 16 * 2048 + 32);
        }

        float st[4][4];
        #pragma unroll
        for (int ktile = 0; ktile < 4; ++ktile) {
            f32x4 s = {0.f, 0.f, 0.f, 0.f};
            __builtin_amdgcn_s_setprio(1);
            s = __builtin_amdgcn_mfma_f32_16x16x32_bf16(ka[2 * ktile], bq[0], s, 0, 0, 0);
            s = __builtin_amdgcn_mfma_f32_16x16x32_bf16(ka[2 * ktile + 1], bq[1], s, 0, 0, 0);
            __builtin_amdgcn_s_setprio(0);
            #pragma unroll
            for (int r = 0; r < 4; ++r) {
                const float p = __expf(s[r] * 0.125f);
                lsum += p;
                st[ktile][r] = p;
            }
        }

        const short* vb = vbp + kt * 64;
        short8 va[8];
        #pragma unroll
        for (int p = 0; p < 2; ++p)
            #pragma unroll
            for (int mt = 0; mt < 4; ++mt)
                va[p * 4 + mt] = *(const short8*)(vb + (size_t)(mt * 16) * CL + p * 32);

        #pragma unroll
        for (int p = 0; p < 2; ++p) {
            short8 pf;
            #pragma unroll
            for (int r = 0; r < 4; ++r) {
                pf[r]     = f2bs(st[2 * p][r]);
                pf[4 + r] = f2bs(st[2 * p + 1][r]);
            }
            __builtin_amdgcn_s_setprio(1);
            #pragma unroll
            for (int mt = 0; mt < 4; ++mt)
                oacc[mt] = __builtin_amdgcn_mfma_f32_16x16x32_bf16(va[p * 4 + mt], pf, oacc[mt], 0, 0, 0);
            __builtin_amdgcn_s_setprio(0);
        }
    }

    lsum += __shfl_xor(lsum, 16, 64);
    lsum += __shfl_xor(lsum, 32, 64);

    float s1 = 0.f, s2 = 0.f;
    {
        const float inv = 1.0f / lsum;
        const size_t grow = rowb + qbase0 + lm;
        #pragma unroll
        for (int mt = 0; mt < 4; ++mt) {
            const size_t base = grow * CD + hoff + mt * 16 + quad * 4;
            const float4 xv = *(const float4*)&x[base];
            const float xa[4] = {xv.x, xv.y, xv.z, xv.w};
            short4v sv;
            #pragma unroll
            for (int r = 0; r < 4; ++r) {
                const float s = xa[r] + oacc[mt][r] * inv;
                s1 += s; s2 += s * s;
                sv[r] = f2bs(s);
            }
            *(short4v*)&sbuf[base] = sv;
        }
    }
    #pragma unroll
    for (int off = 1; off <= 32; off <<= 1) {
        s1 += __shfl_xor(s1, off, 64);
        s2 += __shfl_xor(s2, off, 64);
    }
    if (lane == 0) { red[wave] = s1; red[8 + wave] = s2; }
    __syncthreads();
    if (tid == 0) {
        float t1 = 0.f, t2 = 0.f;
        #pragma unroll
        for (int w = 0; w < 8; ++w) { t1 += red[w]; t2 += red[8 + w]; }
        atomicAdd(&stats[b * 2 + 0], t1);
        atomicAdd(&stats[b * 2 + 1], t2);
    }
}

// ---------------------------------------------------------------------------
// LN apply, vectorized 8 elems/thread
// ---------------------------------------------------------------------------
template <typename TO>
__global__ void ln_apply(const short* __restrict__ s, const float* __restrict__ stats,
                         TO* __restrict__ out, int perBatch) {
    const int bId = blockIdx.y;
    const size_t base = (size_t)bId * perBatch;
    const float n = (float)perBatch;
    const float mean = stats[bId * 2 + 0] / n;
    const float var  = stats[bId * 2 + 1] / n - mean * mean + 1e-5f;
    const float inv  = rsqrtf(var);
    const int stride = gridDim.x * 256 * 8;
    for (int i = (blockIdx.x * 256 + threadIdx.x) * 8; i < perBatch; i += stride) {
        const short8 v8 = *(const short8*)&s[base + i];
        float o[8];
        #pragma unroll
        for (int j = 0; j < 8; ++j) o[j] = (bs2f(v8[j]) - mean) * inv;
        if (sizeof(TO) == 4) {
            float4 f0 = {o[0], o[1], o[2], o[3]}, f1 = {o[4], o[5], o[6], o[7]};
            *(float4*)&((float*)out)[base + i] = f0;
            *(float4*)&((float*)out)[base + i + 4] = f1;
        } else {
            short8 r;
            #pragma unroll
            for (int j = 0; j < 8; ++j) r[j] = f2bs(o[j]);
            *(short8*)&((short*)out)[base + i] = r;
        }
    }
}

// ---------------------------------------------------------------------------
extern "C" void kernel_launch(void* const* d_in, const int* in_sizes, int n_in,
                              void* d_out, int out_size, void* d_ws, size_t ws_size,
                              hipStream_t stream) {
    const float* x  = (const float*)d_in[0];
    const float* wq = (const float*)d_in[1];
    const float* bq = (const float*)d_in[2];
    const float* wk = (const float*)d_in[3];
    const float* bk = (const float*)d_in[4];
    const float* wv = (const float*)d_in[5];
    const float* bv = (const float*)d_in[6];
    const float* w1 = (const float*)d_in[7];
    const float* b1 = (const float*)d_in[8];
    const float* w2 = (const float*)d_in[9];
    const float* b2 = (const float*)d_in[10];

    const int BL = CB * CL;
    const int perBatch = CL * CD;

    // ws layout, 48MB + 64B:
    //   [0,8):   weights: Wqkvt(6MB)+bqkv -> w1t -> w2t
    //   [8,16):  xbf (dead after QKV gemm)
    //   [16,32): qk [4096][2048] (dead after attn)
    //   [32,40): vT [2][1024][2048] (dead after attn)
    //   [8,40):  ff1 (reuse)
    //   [40,48): sbuf/hbuf
    //   [48MB):  stats
    char* ws = (char*)d_ws;
    const size_t MB = 1024 * 1024;
    short* Wqkvt = (short*)(ws);
    float* bqkv  = (float*)(ws + 6 * MB);
    short* w1t   = (short*)(ws);
    short* w2t   = (short*)(ws);
    short* xbf   = (short*)(ws + 8 * MB);
    short* qkb   = (short*)(ws + 16 * MB);
    short* vT    = (short*)(ws + 32 * MB);
    short* ff1   = (short*)(ws + 8 * MB);
    short* hbuf  = (short*)(ws + 40 * MB);
    float* stats = (float*)(ws + 48 * MB);

    dim3 blk(256);

    pack_bias_kernel<<<12, blk, 0, stream>>>(bq, bk, bv, bqkv, stats);
    cvt_x_kernel<<<BL * CD / 1024, blk, 0, stream>>>(x, xbf);
    transpose_qkv<<<dim3(32, 32, 3), blk, 0, stream>>>(wq, wk, wv, Wqkvt);

    // fused QKV: xbf @ Wqkvt^T; q,k -> qkb[row][2048], v -> vT (permuted)
    gemm_mfma<128, 64, 0, 1><<<dim3(3072 / 128, BL / 128), blk, 0, stream>>>(
        xbf, Wqkvt, bqkv, qkb, vT, BL, 3072, CD, nullptr);

    // attention + residual + LN1 stats -> hbuf (s = x + attn)
    attn_mfma<<<dim3(CL / 128, NHEADS, CB), dim3(512), 0, stream>>>(qkb, vT, x, hbuf, stats);

    // LN1 apply in-place
    ln_apply<bf16><<<dim3(128, CB), blk, 0, stream>>>(hbuf, stats, (bf16*)hbuf, perBatch);

    // FFN1
    transpose_cvt<<<dim3(128, 32), blk, 0, stream>>>(w1, w1t, CD, CH, 0);
    gemm_mfma<128, 64, 1, 0><<<dim3(CH / 128, BL / 128), blk, 0, stream>>>(
        hbuf, w1t, b1, ff1, nullptr, BL, CH, CD, nullptr);

    // FFN2 + residual + LN2 stats (BN=64, BK=128: 32 K-iters)
    transpose_cvt<<<dim3(32, 128), blk, 0, stream>>>(w2, w2t, CH, CD, 0);
    gemm_mfma<64, 128, 0, 2><<<dim3(CD / 64, BL / 128), blk, 0, stream>>>(
        ff1, w2t, b2, hbuf, nullptr, BL, CD, CH, stats + 8);

    // LN2 apply -> out fp32
    ln_apply<float><<<dim3(128, CB), blk, 0, stream>>>(hbuf, stats + 8, (float*)d_out, perBatch);
}

// Round 8
// 324.232 us; speedup vs baseline: 1.5791x; 1.5791x over previous
//
#include <hip/hip_runtime.h>
#include <hip/hip_bf16.h>

typedef __hip_bfloat16 bf16;
typedef __attribute__((ext_vector_type(8))) short short8;
typedef __attribute__((ext_vector_type(4))) short short4v;
typedef __attribute__((ext_vector_type(4))) float f32x4;

#define CB 2
#define CL 2048
#define CD 1024
#define CH 4096
#define NHEADS 16
#define DH 64

__device__ __forceinline__ short f2bs(float f) {
    __hip_bfloat16 h = __float2bfloat16(f);
    return *reinterpret_cast<short*>(&h);
}
__device__ __forceinline__ float bs2f(short s) {
    __hip_bfloat16 h = *reinterpret_cast<__hip_bfloat16*>(&s);
    return __bfloat162float(h);
}

__device__ __forceinline__ void async_copy16(const short* g, short* l) {
    __builtin_amdgcn_global_load_lds((const __attribute__((address_space(1))) unsigned int*)g,
                                     (__attribute__((address_space(3))) unsigned int*)l,
                                     16, 0, 0);
}

// pack QKV bias + zero LN stats (one launch)
__global__ void pack_bias_kernel(const float* __restrict__ bq, const float* __restrict__ bk,
                                 const float* __restrict__ bv, float* __restrict__ o,
                                 float* __restrict__ stats) {
    int i = blockIdx.x * 256 + threadIdx.x;
    if (i < 16) stats[i] = 0.0f;
    if (i < 3072) o[i] = i < 1024 ? bq[i] : (i < 2048 ? bk[i - 1024] : bv[i - 2048]);
}

// x fp32 -> bf16, 4 elems/thread
__global__ void cvt_x_kernel(const float* __restrict__ x, short* __restrict__ o) {
    const int i = (blockIdx.x * 256 + threadIdx.x) * 4;
    const float4 v = *(const float4*)&x[i];
    short4v s; s[0] = f2bs(v.x); s[1] = f2bs(v.y); s[2] = f2bs(v.z); s[3] = f2bs(v.w);
    *(short4v*)&o[i] = s;
}

// in[K][N] f32 -> out[row_off + n][k] bf16 (out row stride = K)
__global__ void transpose_cvt(const float* __restrict__ in, short* __restrict__ out,
                              int K, int N, int row_off) {
    __shared__ float T[32][33];
    const int tx = threadIdx.x & 31, ty = threadIdx.x >> 5;
    const int k0 = blockIdx.y * 32, n0 = blockIdx.x * 32;
    #pragma unroll
    for (int i = 0; i < 4; ++i)
        T[ty + i * 8][tx] = in[(size_t)(k0 + ty + i * 8) * N + n0 + tx];
    __syncthreads();
    #pragma unroll
    for (int i = 0; i < 4; ++i)
        out[(size_t)(row_off + n0 + ty + i * 8) * K + k0 + tx] = f2bs(T[tx][ty + i * 8]);
}

// 3 QKV weight transposes in one launch (z selects source)
__global__ void transpose_qkv(const float* __restrict__ wq, const float* __restrict__ wk,
                              const float* __restrict__ wv, short* __restrict__ out) {
    __shared__ float T[32][33];
    const int z = blockIdx.z;
    const float* in = z == 0 ? wq : (z == 1 ? wk : wv);
    const int row_off = z * 1024;
    const int tx = threadIdx.x & 31, ty = threadIdx.x >> 5;
    const int k0 = blockIdx.y * 32, n0 = blockIdx.x * 32;
    #pragma unroll
    for (int i = 0; i < 4; ++i)
        T[ty + i * 8][tx] = in[(size_t)(k0 + ty + i * 8) * CD + n0 + tx];
    __syncthreads();
    #pragma unroll
    for (int i = 0; i < 4; ++i)
        out[(size_t)(row_off + n0 + ty + i * 8) * CD + k0 + tx] = f2bs(T[tx][ty + i * 8]);
}

// ---------------------------------------------------------------------------
// MFMA GEMM (R2-exact single-buffer structure; W = waves/block).
// BM=128, BK slabs in LDS, staged chunk-linearly (chunk c -> &As[c*8]).
// Measured model (R2-R5): duration = staged-bytes / ~10.7 TB/s at >=2
// blocks/CU; schedule variants don't change it; only tile AI does.
// W=4: 256 thr, 2x2 waves, wave owns 64 x BN/2.
// W=8: 512 thr, 2x4 waves, wave owns 64 x BN/4 (use when BN=256 keeps
//      grid at 2 blocks/CU: AI 85 vs 64).
// Grid must be (N/BN, 32). XCD swizzle: linear id % 8.
// EPI 0: C = act(acc+bias)
// EPI 1: QKV split: col<2048 -> qk[row*2048+col]; col>=2048 -> vT permuted:
//        within each 64-key group, key k -> pos (k5,k3,k2,k4,k1,k0) so attn's
//        PV A-fragment is one contiguous 16B read.
// EPI 2: LN2: v += C(hbuf); in-place write; atomicAdd (sum,sumsq) -> stats
// ---------------------------------------------------------------------------
template <int BN, int BK, int RELU, int EPI, int W>
__launch_bounds__(W * 64)
__global__ void gemm_mfma(const short* __restrict__ A,
                          const short* __restrict__ Bt,
                          const float* __restrict__ bias,
                          short* __restrict__ C,
                          short* __restrict__ C2,
                          int M, int N, int K,
                          float* __restrict__ stats) {
    constexpr int THREADS = W * 64;
    constexpr int WN = W / 2;                // wave columns
    constexpr int NT = BN / (WN * 16);       // n-tiles per wave
    constexpr int KH = BK / 32;              // slabs
    constexpr int ACH = 16 * BK;             // A chunks total
    constexpr int BCH = BN * BK / 8;         // B chunks total
    __shared__ short As[128 * BK];           // slab s = chunks [s*512, s*512+512)
    __shared__ short Bs[BN * BK];            // slab s = chunks [s*BN*4, ...)
    __shared__ float red[2 * W];

    const int tid = threadIdx.x;
    const int wave = tid >> 6, lane = tid & 63, quad = lane >> 4, lm = lane & 15;
    const int wm = (wave & 1) * 64, wn = (wave >> 1) * (NT * 16);

    // XCD-aware swizzle (assumes gridDim.y == 32, hw xcd = linear id % 8)
    const int id = blockIdx.y * gridDim.x + blockIdx.x;
    const int xcd = id & 7, within = id >> 3;
    const int by = xcd * 4 + (within & 3);
    const int bx = within >> 2;
    const int row0 = by * 128, col0 = bx * BN;

    f32x4 acc[4][NT];
    #pragma unroll
    for (int i = 0; i < 4; ++i)
        #pragma unroll
        for (int j = 0; j < NT; ++j) { f32x4 z = {0.f, 0.f, 0.f, 0.f}; acc[i][j] = z; }

    for (int k0 = 0; k0 < K; k0 += BK) {
        // A: chunk-linear (slab = 512 chunks of 16B = 128 rows x 32 k)
        #pragma unroll
        for (int t = 0; t < ACH / THREADS; ++t) {
            const int c = t * THREADS + tid;
            const int slab = c >> 9, idx = c & 511;
            const int r = idx >> 2, seg = idx & 3;
            async_copy16(A + (size_t)(row0 + r) * K + k0 + slab * 32 + seg * 8, &As[c * 8]);
        }
        // B: chunk-linear (slab = BN*4 chunks)
        #pragma unroll
        for (int t = 0; t < BCH / THREADS; ++t) {
            const int c = t * THREADS + tid;
            const int slab = c / (BN * 4), idx = c % (BN * 4);
            const int r = idx >> 2, seg = idx & 3;
            async_copy16(Bt + (size_t)(col0 + r) * K + k0 + slab * 32 + seg * 8, &Bs[c * 8]);
        }
        __syncthreads();

        #pragma unroll
        for (int kh = 0; kh < KH; ++kh) {
            short8 af[4], bfr[NT];
            #pragma unroll
            for (int mt = 0; mt < 4; ++mt)
                af[mt] = *(const short8*)&As[kh * 4096 + (wm + mt * 16 + lm) * 32 + quad * 8];
            #pragma unroll
            for (int nt = 0; nt < NT; ++nt)
                bfr[nt] = *(const short8*)&Bs[kh * (BN * 32) + (wn + nt * 16 + lm) * 32 + quad * 8];
            #pragma unroll
            for (int mt = 0; mt < 4; ++mt)
                #pragma unroll
                for (int nt = 0; nt < NT; ++nt)
                    acc[mt][nt] = __builtin_amdgcn_mfma_f32_16x16x32_bf16(af[mt], bfr[nt], acc[mt][nt], 0, 0, 0);
        }
        __syncthreads();
    }

    float s1 = 0.f, s2 = 0.f;
    #pragma unroll
    for (int mt = 0; mt < 4; ++mt) {
        #pragma unroll
        for (int nt = 0; nt < NT; ++nt) {
            const int col = col0 + wn + nt * 16 + lm;
            const float bv = bias[col];
            const int rowb = row0 + wm + mt * 16 + quad * 4;
            if (EPI == 1 && col >= 2048) {
                const int b = row0 >> 11;
                const int l0 = rowb & (CL - 1);
                // key permutation within 64-group: k5,k4,k3,k2 -> c5=k5,
                // c4=k3, c3=k2, c2=k4 (k1k0=0 here; store stays 4-aligned)
                const int lp = (l0 & ~63) | (l0 & 32) | ((l0 & 12) << 1) | ((l0 & 16) >> 2);
                short4v sv;
                #pragma unroll
                for (int r = 0; r < 4; ++r) sv[r] = f2bs(acc[mt][nt][r] + bv);
                *(short4v*)&C2[(size_t)b * CD * CL + (size_t)(col - 2048) * CL + lp] = sv;
            } else {
                #pragma unroll
                for (int r = 0; r < 4; ++r) {
                    float v = acc[mt][nt][r] + bv;
                    if (RELU) v = fmaxf(v, 0.f);
                    const int ld = (EPI == 1) ? 2048 : N;
                    const size_t idx = (size_t)(rowb + r) * ld + col;
                    if (EPI == 2) {
                        v += bs2f(C[idx]);
                        s1 += v; s2 += v * v;
                    }
                    C[idx] = f2bs(v);
                }
            }
        }
    }
    if (EPI == 2) {
        #pragma unroll
        for (int off = 1; off <= 32; off <<= 1) {
            s1 += __shfl_xor(s1, off, 64);
            s2 += __shfl_xor(s2, off, 64);
        }
        if (lane == 0) { red[wave] = s1; red[W + wave] = s2; }
        __syncthreads();
        if (tid == 0) {
            const int batch = row0 >> 11;
            float t1 = 0.f, t2 = 0.f;
            #pragma unroll
            for (int w = 0; w < W; ++w) { t1 += red[w]; t2 += red[W + w]; }
            atomicAdd(&stats[batch * 2 + 0], t1);
            atomicAdd(&stats[batch * 2 + 1], t2);
        }
    }
}

// ---------------------------------------------------------------------------
// Attention (R1-proposal, proven at 345.6): S^T formulation, KT=64 keys/iter,
// dense PV. 8 waves x 16 q-rows (512 threads) -> 16 waves/CU. V pre-permuted
// in global (gemm EPI 1) so the PV A-fragment is ONE swizzled b128 read.
// K & V staged via global_load_lds with 16B-chunk XOR swizzle (linear LDS
// dest + inverse-swizzled global source + swizzled read; staging shares K/V
// across all 8 waves — R7 showed direct L2 reads 8x the request traffic).
// 2-phase double-buffer: stage(next) before compute(cur), one barrier/tile.
// ---------------------------------------------------------------------------
__launch_bounds__(512)
__global__ void attn_mfma(const short* __restrict__ qk,
                          const short* __restrict__ vT,
                          const float* __restrict__ x,
                          short* __restrict__ sbuf,
                          float* __restrict__ stats) {
    __shared__ short Ks[2][64 * 64];    // [key64][dh64] swizzled, dbuf, 16 KB
    __shared__ short Vs[2][64 * 64];    // [dh64][key64] permuted+swizzled, 16 KB
    __shared__ float red[16];

    const int tid = threadIdx.x;
    const int wave = tid >> 6, lane = tid & 63, quad = lane >> 4, lm = lane & 15;
    const int sx = lm & 7;              // = (row & 7) for all fragment rows

    const int id = blockIdx.z * (16 * 16) + blockIdx.y * 16 + blockIdx.x;
    const int xcd = id & 7, rest = id >> 3;
    const int qx = rest & 15, gq = rest >> 4;
    const int g = gq * 8 + xcd;
    const int h = g & 15, b = g >> 4;

    const int hoff = h * DH;
    const size_t rowb = (size_t)b * CL;
    const size_t vbase = (size_t)b * CD * CL + (size_t)hoff * CL;
    const int qbase0 = qx * 128 + wave * 16;

    short8 bq[2];
    #pragma unroll
    for (int kf = 0; kf < 2; ++kf)
        bq[kf] = *(const short8*)(qk + (rowb + qbase0 + lm) * 2048 + hoff + kf * 32 + quad * 8);

    f32x4 oacc[4];
    #pragma unroll
    for (int mt = 0; mt < 4; ++mt) { f32x4 z = {0.f, 0.f, 0.f, 0.f}; oacc[mt] = z; }
    float lsum = 0.f;

    auto stage = [&](int buf, int kt) {
        {
            const int key = tid >> 3, sp = tid & 7;
            async_copy16(qk + (rowb + kt * 64 + key) * 2048 + 1024 + hoff + ((sp ^ (key & 7)) * 8),
                         &Ks[buf][tid * 8]);
        }
        {
            const int row = tid >> 3, sp = tid & 7;
            async_copy16(vT + vbase + (size_t)row * CL + kt * 64 + ((sp ^ (row & 7)) * 8),
                         &Vs[buf][tid * 8]);
        }
    };

    stage(0, 0);
    __syncthreads();            // drain prologue stage
    int cur = 0;

    for (int kt = 0; kt < CL / 64; ++kt) {
        if (kt + 1 < CL / 64) stage(cur ^ 1, kt + 1);   // in-flight across compute
        const short* K_ = &Ks[cur][0];
        const short* V_ = &Vs[cur][0];

        float st[4][4];
        #pragma unroll
        for (int ktile = 0; ktile < 4; ++ktile) {
            const int krow = ktile * 16 + lm;
            const int s0 = (quad ^ sx) << 3;            // swizzled seg, 16B chunks
            const short8 a0 = *(const short8*)&K_[krow * 64 + s0];
            const short8 a1 = *(const short8*)&K_[krow * 64 + (s0 ^ 32)];
            f32x4 s = {0.f, 0.f, 0.f, 0.f};
            __builtin_amdgcn_s_setprio(1);
            s = __builtin_amdgcn_mfma_f32_16x16x32_bf16(a0, bq[0], s, 0, 0, 0);
            s = __builtin_amdgcn_mfma_f32_16x16x32_bf16(a1, bq[1], s, 0, 0, 0);
            __builtin_amdgcn_s_setprio(0);
            #pragma unroll
            for (int r = 0; r < 4; ++r) {
                const float p = __expf(s[r] * 0.125f);
                lsum += p;
                st[ktile][r] = p;
            }
        }

        #pragma unroll
        for (int p = 0; p < 2; ++p) {
            short8 pf;
            #pragma unroll
            for (int r = 0; r < 4; ++r) {
                pf[r]     = f2bs(st[2 * p][r]);
                pf[4 + r] = f2bs(st[2 * p + 1][r]);
            }
            #pragma unroll
            for (int mt = 0; mt < 4; ++mt) {
                const int sc = (p * 4 + quad) ^ sx;     // swizzled 16B chunk
                const short8 vf = *(const short8*)&V_[(mt * 16 + lm) * 64 + sc * 8];
                __builtin_amdgcn_s_setprio(1);
                oacc[mt] = __builtin_amdgcn_mfma_f32_16x16x32_bf16(vf, pf, oacc[mt], 0, 0, 0);
                __builtin_amdgcn_s_setprio(0);
            }
        }
        __syncthreads();        // next tile staged + lds reads of cur done
        cur ^= 1;
    }

    lsum += __shfl_xor(lsum, 16, 64);
    lsum += __shfl_xor(lsum, 32, 64);

    float s1 = 0.f, s2 = 0.f;
    {
        const float inv = 1.0f / lsum;
        const size_t grow = rowb + qbase0 + lm;
        #pragma unroll
        for (int mt = 0; mt < 4; ++mt) {
            const size_t base = grow * CD + hoff + mt * 16 + quad * 4;
            const float4 xv = *(const float4*)&x[base];
            const float xa[4] = {xv.x, xv.y, xv.z, xv.w};
            short4v sv;
            #pragma unroll
            for (int r = 0; r < 4; ++r) {
                const float s = xa[r] + oacc[mt][r] * inv;
                s1 += s; s2 += s * s;
                sv[r] = f2bs(s);
            }
            *(short4v*)&sbuf[base] = sv;
        }
    }
    #pragma unroll
    for (int off = 1; off <= 32; off <<= 1) {
        s1 += __shfl_xor(s1, off, 64);
        s2 += __shfl_xor(s2, off, 64);
    }
    if (lane == 0) { red[wave] = s1; red[8 + wave] = s2; }
    __syncthreads();
    if (tid == 0) {
        float t1 = 0.f, t2 = 0.f;
        #pragma unroll
        for (int w = 0; w < 8; ++w) { t1 += red[w]; t2 += red[8 + w]; }
        atomicAdd(&stats[b * 2 + 0], t1);
        atomicAdd(&stats[b * 2 + 1], t2);
    }
}

// ---------------------------------------------------------------------------
// LN apply, vectorized 8 elems/thread
// ---------------------------------------------------------------------------
template <typename TO>
__global__ void ln_apply(const short* __restrict__ s, const float* __restrict__ stats,
                         TO* __restrict__ out, int perBatch) {
    const int bId = blockIdx.y;
    const size_t base = (size_t)bId * perBatch;
    const float n = (float)perBatch;
    const float mean = stats[bId * 2 + 0] / n;
    const float var  = stats[bId * 2 + 1] / n - mean * mean + 1e-5f;
    const float inv  = rsqrtf(var);
    const int stride = gridDim.x * 256 * 8;
    for (int i = (blockIdx.x * 256 + threadIdx.x) * 8; i < perBatch; i += stride) {
        const short8 v8 = *(const short8*)&s[base + i];
        float o[8];
        #pragma unroll
        for (int j = 0; j < 8; ++j) o[j] = (bs2f(v8[j]) - mean) * inv;
        if (sizeof(TO) == 4) {
            float4 f0 = {o[0], o[1], o[2], o[3]}, f1 = {o[4], o[5], o[6], o[7]};
            *(float4*)&((float*)out)[base + i] = f0;
            *(float4*)&((float*)out)[base + i + 4] = f1;
        } else {
            short8 r;
            #pragma unroll
            for (int j = 0; j < 8; ++j) r[j] = f2bs(o[j]);
            *(short8*)&((short*)out)[base + i] = r;
        }
    }
}

// ---------------------------------------------------------------------------
extern "C" void kernel_launch(void* const* d_in, const int* in_sizes, int n_in,
                              void* d_out, int out_size, void* d_ws, size_t ws_size,
                              hipStream_t stream) {
    const float* x  = (const float*)d_in[0];
    const float* wq = (const float*)d_in[1];
    const float* bq = (const float*)d_in[2];
    const float* wk = (const float*)d_in[3];
    const float* bk = (const float*)d_in[4];
    const float* wv = (const float*)d_in[5];
    const float* bv = (const float*)d_in[6];
    const float* w1 = (const float*)d_in[7];
    const float* b1 = (const float*)d_in[8];
    const float* w2 = (const float*)d_in[9];
    const float* b2 = (const float*)d_in[10];

    const int BL = CB * CL;
    const int perBatch = CL * CD;

    // ws layout, 48MB + 64B:
    //   [0,8):   weights: Wqkvt(6MB)+bqkv -> w1t -> w2t
    //   [8,16):  xbf (dead after QKV gemm)
    //   [16,32): qk [4096][2048] (dead after attn)
    //   [32,40): vT [2][1024][2048] (dead after attn)
    //   [8,40):  ff1 (reuse)
    //   [40,48): sbuf/hbuf
    //   [48MB):  stats
    char* ws = (char*)d_ws;
    const size_t MB = 1024 * 1024;
    short* Wqkvt = (short*)(ws);
    float* bqkv  = (float*)(ws + 6 * MB);
    short* w1t   = (short*)(ws);
    short* w2t   = (short*)(ws);
    short* xbf   = (short*)(ws + 8 * MB);
    short* qkb   = (short*)(ws + 16 * MB);
    short* vT    = (short*)(ws + 32 * MB);
    short* ff1   = (short*)(ws + 8 * MB);
    short* hbuf  = (short*)(ws + 40 * MB);
    float* stats = (float*)(ws + 48 * MB);

    dim3 blk(256);

    pack_bias_kernel<<<12, blk, 0, stream>>>(bq, bk, bv, bqkv, stats);
    cvt_x_kernel<<<BL * CD / 1024, blk, 0, stream>>>(x, xbf);
    transpose_qkv<<<dim3(32, 32, 3), blk, 0, stream>>>(wq, wk, wv, Wqkvt);

    // fused QKV: xbf @ Wqkvt^T; q,k -> qkb[row][2048], v -> vT (permuted)
    gemm_mfma<128, 64, 0, 1, 4><<<dim3(3072 / 128, BL / 128), blk, 0, stream>>>(
        xbf, Wqkvt, bqkv, qkb, vT, BL, 3072, CD, nullptr);

    // attention + residual + LN1 stats -> hbuf (s = x + attn)
    attn_mfma<<<dim3(CL / 128, NHEADS, CB), dim3(512), 0, stream>>>(qkb, vT, x, hbuf, stats);

    // LN1 apply in-place
    ln_apply<bf16><<<dim3(128, CB), blk, 0, stream>>>(hbuf, stats, (bf16*)hbuf, perBatch);

    // FFN1: BN=256 (AI 85 vs 64 -> staged bytes 524->393MB), W=8 (512 thr),
    // grid (16,32)=512 blocks = 2 blocks/CU (the proven-BW regime).
    transpose_cvt<<<dim3(128, 32), blk, 0, stream>>>(w1, w1t, CD, CH, 0);
    gemm_mfma<256, 64, 1, 0, 8><<<dim3(CH / 256, BL / 128), dim3(512), 0, stream>>>(
        hbuf, w1t, b1, ff1, nullptr, BL, CH, CD, nullptr);

    // FFN2 + residual + LN2 stats (R2-exact best: BN=64, BK=128)
    transpose_cvt<<<dim3(32, 128), blk, 0, stream>>>(w2, w2t, CH, CD, 0);
    gemm_mfma<64, 128, 0, 2, 4><<<dim3(CD / 64, BL / 128), blk, 0, stream>>>(
        ff1, w2t, b2, hbuf, nullptr, BL, CD, CH, stats + 8);

    // LN2 apply -> out fp32
    ln_apply<float><<<dim3(128, CB), blk, 0, stream>>>(hbuf, stats + 8, (float*)d_out, perBatch);
}

// Round 9
// 319.228 us; speedup vs baseline: 1.6039x; 1.0157x over previous
//
#include <hip/hip_runtime.h>
#include <hip/hip_bf16.h>

typedef __hip_bfloat16 bf16;
typedef __attribute__((ext_vector_type(8))) short short8;
typedef __attribute__((ext_vector_type(4))) short short4v;
typedef __attribute__((ext_vector_type(4))) float f32x4;

#define CB 2
#define CL 2048
#define CD 1024
#define CH 4096
#define NHEADS 16
#define DH 64

__device__ __forceinline__ short f2bs(float f) {
    __hip_bfloat16 h = __float2bfloat16(f);
    return *reinterpret_cast<short*>(&h);
}
__device__ __forceinline__ float bs2f(short s) {
    __hip_bfloat16 h = *reinterpret_cast<__hip_bfloat16*>(&s);
    return __bfloat162float(h);
}

__device__ __forceinline__ void async_copy16(const short* g, short* l) {
    __builtin_amdgcn_global_load_lds((const __attribute__((address_space(1))) unsigned int*)g,
                                     (__attribute__((address_space(3))) unsigned int*)l,
                                     16, 0, 0);
}

// pack QKV bias + zero LN stats (one launch)
__global__ void pack_bias_kernel(const float* __restrict__ bq, const float* __restrict__ bk,
                                 const float* __restrict__ bv, float* __restrict__ o,
                                 float* __restrict__ stats) {
    int i = blockIdx.x * 256 + threadIdx.x;
    if (i < 16) stats[i] = 0.0f;
    if (i < 3072) o[i] = i < 1024 ? bq[i] : (i < 2048 ? bk[i - 1024] : bv[i - 2048]);
}

// x fp32 -> bf16, 4 elems/thread
__global__ void cvt_x_kernel(const float* __restrict__ x, short* __restrict__ o) {
    const int i = (blockIdx.x * 256 + threadIdx.x) * 4;
    const float4 v = *(const float4*)&x[i];
    short4v s; s[0] = f2bs(v.x); s[1] = f2bs(v.y); s[2] = f2bs(v.z); s[3] = f2bs(v.w);
    *(short4v*)&o[i] = s;
}

// in[K][N] f32 -> out[row_off + n][k] bf16 (out row stride = K)
__global__ void transpose_cvt(const float* __restrict__ in, short* __restrict__ out,
                              int K, int N, int row_off) {
    __shared__ float T[32][33];
    const int tx = threadIdx.x & 31, ty = threadIdx.x >> 5;
    const int k0 = blockIdx.y * 32, n0 = blockIdx.x * 32;
    #pragma unroll
    for (int i = 0; i < 4; ++i)
        T[ty + i * 8][tx] = in[(size_t)(k0 + ty + i * 8) * N + n0 + tx];
    __syncthreads();
    #pragma unroll
    for (int i = 0; i < 4; ++i)
        out[(size_t)(row_off + n0 + ty + i * 8) * K + k0 + tx] = f2bs(T[tx][ty + i * 8]);
}

// 3 QKV weight transposes in one launch (z selects source)
__global__ void transpose_qkv(const float* __restrict__ wq, const float* __restrict__ wk,
                              const float* __restrict__ wv, short* __restrict__ out) {
    __shared__ float T[32][33];
    const int z = blockIdx.z;
    const float* in = z == 0 ? wq : (z == 1 ? wk : wv);
    const int row_off = z * 1024;
    const int tx = threadIdx.x & 31, ty = threadIdx.x >> 5;
    const int k0 = blockIdx.y * 32, n0 = blockIdx.x * 32;
    #pragma unroll
    for (int i = 0; i < 4; ++i)
        T[ty + i * 8][tx] = in[(size_t)(k0 + ty + i * 8) * CD + n0 + tx];
    __syncthreads();
    #pragma unroll
    for (int i = 0; i < 4; ++i)
        out[(size_t)(row_off + n0 + ty + i * 8) * CD + k0 + tx] = f2bs(T[tx][ty + i * 8]);
}

// ---------------------------------------------------------------------------
// MFMA GEMM (single-buffer m97 structure; W = waves/block).
// BM=128, BK slabs in LDS, staged chunk-linearly (chunk c -> &As[c*8]).
// Measured model (R2-R8): duration = staged-bytes / ~10.7 TB/s at >=2
// blocks/CU; schedule variants don't change it; only tile AI does.
// W=4: 256 thr, 2x2 waves. W=8: 512 thr, 2x4 waves (for BN in {192,256}
// keeping grid at 2 blocks/CU).
// Grid must be (N/BN, 32). XCD swizzle: linear id % 8.
// EPI 0: C = act(acc+bias)
// EPI 1: QKV split: col<2048 -> qk[row*2048+col]; col>=2048 -> vT permuted:
//        within each 64-key group, key k -> pos (k5,k3,k2,k4,k1,k0) so attn's
//        PV A-fragment is one contiguous 16B read.
// EPI 2: LN2: v += C(hbuf); in-place write; atomicAdd (sum,sumsq) -> stats
// ---------------------------------------------------------------------------
template <int BN, int BK, int RELU, int EPI, int W>
__launch_bounds__(W * 64)
__global__ void gemm_mfma(const short* __restrict__ A,
                          const short* __restrict__ Bt,
                          const float* __restrict__ bias,
                          short* __restrict__ C,
                          short* __restrict__ C2,
                          int M, int N, int K,
                          float* __restrict__ stats) {
    constexpr int THREADS = W * 64;
    constexpr int WN = W / 2;                // wave columns
    constexpr int NT = BN / (WN * 16);       // n-tiles per wave
    constexpr int KH = BK / 32;              // slabs
    constexpr int ACH = 16 * BK;             // A chunks total
    constexpr int BCH = BN * BK / 8;         // B chunks total
    __shared__ short As[128 * BK];           // slab s = chunks [s*512, s*512+512)
    __shared__ short Bs[BN * BK];            // slab s = chunks [s*BN*4, ...)
    __shared__ float red[2 * W];

    const int tid = threadIdx.x;
    const int wave = tid >> 6, lane = tid & 63, quad = lane >> 4, lm = lane & 15;
    const int wm = (wave & 1) * 64, wn = (wave >> 1) * (NT * 16);

    // XCD-aware swizzle (assumes gridDim.y == 32, hw xcd = linear id % 8)
    const int id = blockIdx.y * gridDim.x + blockIdx.x;
    const int xcd = id & 7, within = id >> 3;
    const int by = xcd * 4 + (within & 3);
    const int bx = within >> 2;
    const int row0 = by * 128, col0 = bx * BN;

    f32x4 acc[4][NT];
    #pragma unroll
    for (int i = 0; i < 4; ++i)
        #pragma unroll
        for (int j = 0; j < NT; ++j) { f32x4 z = {0.f, 0.f, 0.f, 0.f}; acc[i][j] = z; }

    for (int k0 = 0; k0 < K; k0 += BK) {
        // A: chunk-linear (slab = 512 chunks of 16B = 128 rows x 32 k)
        #pragma unroll
        for (int t = 0; t < ACH / THREADS; ++t) {
            const int c = t * THREADS + tid;
            const int slab = c >> 9, idx = c & 511;
            const int r = idx >> 2, seg = idx & 3;
            async_copy16(A + (size_t)(row0 + r) * K + k0 + slab * 32 + seg * 8, &As[c * 8]);
        }
        // B: chunk-linear (slab = BN*4 chunks)
        #pragma unroll
        for (int t = 0; t < BCH / THREADS; ++t) {
            const int c = t * THREADS + tid;
            const int slab = c / (BN * 4), idx = c % (BN * 4);
            const int r = idx >> 2, seg = idx & 3;
            async_copy16(Bt + (size_t)(col0 + r) * K + k0 + slab * 32 + seg * 8, &Bs[c * 8]);
        }
        __syncthreads();

        #pragma unroll
        for (int kh = 0; kh < KH; ++kh) {
            short8 af[4], bfr[NT];
            #pragma unroll
            for (int mt = 0; mt < 4; ++mt)
                af[mt] = *(const short8*)&As[kh * 4096 + (wm + mt * 16 + lm) * 32 + quad * 8];
            #pragma unroll
            for (int nt = 0; nt < NT; ++nt)
                bfr[nt] = *(const short8*)&Bs[kh * (BN * 32) + (wn + nt * 16 + lm) * 32 + quad * 8];
            #pragma unroll
            for (int mt = 0; mt < 4; ++mt)
                #pragma unroll
                for (int nt = 0; nt < NT; ++nt)
                    acc[mt][nt] = __builtin_amdgcn_mfma_f32_16x16x32_bf16(af[mt], bfr[nt], acc[mt][nt], 0, 0, 0);
        }
        __syncthreads();
    }

    float s1 = 0.f, s2 = 0.f;
    #pragma unroll
    for (int mt = 0; mt < 4; ++mt) {
        #pragma unroll
        for (int nt = 0; nt < NT; ++nt) {
            const int col = col0 + wn + nt * 16 + lm;
            const float bv = bias[col];
            const int rowb = row0 + wm + mt * 16 + quad * 4;
            if (EPI == 1 && col >= 2048) {
                const int b = row0 >> 11;
                const int l0 = rowb & (CL - 1);
                // key permutation within 64-group: k5,k4,k3,k2 -> c5=k5,
                // c4=k3, c3=k2, c2=k4 (k1k0=0 here; store stays 4-aligned)
                const int lp = (l0 & ~63) | (l0 & 32) | ((l0 & 12) << 1) | ((l0 & 16) >> 2);
                short4v sv;
                #pragma unroll
                for (int r = 0; r < 4; ++r) sv[r] = f2bs(acc[mt][nt][r] + bv);
                *(short4v*)&C2[(size_t)b * CD * CL + (size_t)(col - 2048) * CL + lp] = sv;
            } else {
                #pragma unroll
                for (int r = 0; r < 4; ++r) {
                    float v = acc[mt][nt][r] + bv;
                    if (RELU) v = fmaxf(v, 0.f);
                    const int ld = (EPI == 1) ? 2048 : N;
                    const size_t idx = (size_t)(rowb + r) * ld + col;
                    if (EPI == 2) {
                        v += bs2f(C[idx]);
                        s1 += v; s2 += v * v;
                    }
                    C[idx] = f2bs(v);
                }
            }
        }
    }
    if (EPI == 2) {
        #pragma unroll
        for (int off = 1; off <= 32; off <<= 1) {
            s1 += __shfl_xor(s1, off, 64);
            s2 += __shfl_xor(s2, off, 64);
        }
        if (lane == 0) { red[wave] = s1; red[W + wave] = s2; }
        __syncthreads();
        if (tid == 0) {
            const int batch = row0 >> 11;
            float t1 = 0.f, t2 = 0.f;
            #pragma unroll
            for (int w = 0; w < W; ++w) { t1 += red[w]; t2 += red[W + w]; }
            atomicAdd(&stats[batch * 2 + 0], t1);
            atomicAdd(&stats[batch * 2 + 1], t2);
        }
    }
}

// ---------------------------------------------------------------------------
// Attention, S^T formulation, dense PV. R9: KT=128 keys/iter (16 iters,
// halving the per-tile barrier + vmcnt-drain count that dominates the gap
// to component floors). 8 waves x 16 q-rows (512 threads). V pre-permuted
// in global (gemm EPI 1) so the PV A-fragment is ONE swizzled b128 read.
// K staged with 8-chunk XOR swizzle (row stride 128B), V with 16-chunk XOR
// swizzle (row stride 256B): linear LDS dest + inverse-swizzled global
// source + swizzled read; residual conflicts 2-way = free.
// 2-phase double-buffer: stage(next) before compute(cur), one barrier/tile.
// ---------------------------------------------------------------------------
__launch_bounds__(512)
__global__ void attn_mfma(const short* __restrict__ qk,
                          const short* __restrict__ vT,
                          const float* __restrict__ x,
                          short* __restrict__ sbuf,
                          float* __restrict__ stats) {
    __shared__ short Ks[2][128 * 64];   // [key128][dh64] swizzled, dbuf, 32 KB
    __shared__ short Vs[2][64 * 128];   // [dh64][key128] permuted+swizzled, 32 KB
    __shared__ float red[16];

    const int tid = threadIdx.x;
    const int wave = tid >> 6, lane = tid & 63, quad = lane >> 4, lm = lane & 15;
    const int sx = lm & 7;              // K-row swizzle key (8 chunks/row)

    const int id = blockIdx.z * (16 * 16) + blockIdx.y * 16 + blockIdx.x;
    const int xcd = id & 7, rest = id >> 3;
    const int qx = rest & 15, gq = rest >> 4;
    const int g = gq * 8 + xcd;
    const int h = g & 15, b = g >> 4;

    const int hoff = h * DH;
    const size_t rowb = (size_t)b * CL;
    const size_t vbase = (size_t)b * CD * CL + (size_t)hoff * CL;
    const int qbase0 = qx * 128 + wave * 16;

    short8 bq[2];
    #pragma unroll
    for (int kf = 0; kf < 2; ++kf)
        bq[kf] = *(const short8*)(qk + (rowb + qbase0 + lm) * 2048 + hoff + kf * 32 + quad * 8);

    f32x4 oacc[4];
    #pragma unroll
    for (int mt = 0; mt < 4; ++mt) { f32x4 z = {0.f, 0.f, 0.f, 0.f}; oacc[mt] = z; }
    float lsum = 0.f;

    // Stage K/V tile kt (128 keys). LDS dest linear in chunk c; global
    // SOURCE chunk XOR-permuted so the swizzled read recovers logical data.
    auto stage = [&](int buf, int kt) {
        #pragma unroll
        for (int t = 0; t < 2; ++t) {
            const int c = tid + t * 512;
            const int key = c >> 3, sp = c & 7;
            async_copy16(qk + (rowb + kt * 128 + key) * 2048 + 1024 + hoff + ((sp ^ (key & 7)) * 8),
                         &Ks[buf][c * 8]);
        }
        #pragma unroll
        for (int t = 0; t < 2; ++t) {
            const int c = tid + t * 512;
            const int row = c >> 4, sp = c & 15;
            async_copy16(vT + vbase + (size_t)row * CL + kt * 128 + ((sp ^ (row & 15)) * 8),
                         &Vs[buf][c * 8]);
        }
    };

    stage(0, 0);
    __syncthreads();            // drain prologue stage
    int cur = 0;

    for (int kt = 0; kt < CL / 128; ++kt) {
        if (kt + 1 < CL / 128) stage(cur ^ 1, kt + 1);  // in-flight across compute
        const short* K_ = &Ks[cur][0];
        const short* V_ = &Vs[cur][0];

        float st[8][4];
        #pragma unroll
        for (int ktile = 0; ktile < 8; ++ktile) {
            const int krow = ktile * 16 + lm;
            const int s0 = (quad ^ sx) << 3;            // swizzled seg, 16B chunks
            const short8 a0 = *(const short8*)&K_[krow * 64 + s0];
            const short8 a1 = *(const short8*)&K_[krow * 64 + (s0 ^ 32)];
            f32x4 s = {0.f, 0.f, 0.f, 0.f};
            __builtin_amdgcn_s_setprio(1);
            s = __builtin_amdgcn_mfma_f32_16x16x32_bf16(a0, bq[0], s, 0, 0, 0);
            s = __builtin_amdgcn_mfma_f32_16x16x32_bf16(a1, bq[1], s, 0, 0, 0);
            __builtin_amdgcn_s_setprio(0);
            #pragma unroll
            for (int r = 0; r < 4; ++r) {
                const float p = __expf(s[r] * 0.125f);
                lsum += p;
                st[ktile][r] = p;
            }
        }

        #pragma unroll
        for (int p = 0; p < 4; ++p) {
            short8 pf;
            #pragma unroll
            for (int r = 0; r < 4; ++r) {
                pf[r]     = f2bs(st[2 * p][r]);
                pf[4 + r] = f2bs(st[2 * p + 1][r]);
            }
            #pragma unroll
            for (int mt = 0; mt < 4; ++mt) {
                const int sc = (p * 4 + quad) ^ lm;     // 16-chunk swizzle (row&15 = lm)
                const short8 vf = *(const short8*)&V_[(mt * 16 + lm) * 128 + sc * 8];
                __builtin_amdgcn_s_setprio(1);
                oacc[mt] = __builtin_amdgcn_mfma_f32_16x16x32_bf16(vf, pf, oacc[mt], 0, 0, 0);
                __builtin_amdgcn_s_setprio(0);
            }
        }
        __syncthreads();        // next tile staged + lds reads of cur done
        cur ^= 1;
    }

    lsum += __shfl_xor(lsum, 16, 64);
    lsum += __shfl_xor(lsum, 32, 64);

    float s1 = 0.f, s2 = 0.f;
    {
        const float inv = 1.0f / lsum;
        const size_t grow = rowb + qbase0 + lm;
        #pragma unroll
        for (int mt = 0; mt < 4; ++mt) {
            const size_t base = grow * CD + hoff + mt * 16 + quad * 4;
            const float4 xv = *(const float4*)&x[base];
            const float xa[4] = {xv.x, xv.y, xv.z, xv.w};
            short4v sv;
            #pragma unroll
            for (int r = 0; r < 4; ++r) {
                const float s = xa[r] + oacc[mt][r] * inv;
                s1 += s; s2 += s * s;
                sv[r] = f2bs(s);
            }
            *(short4v*)&sbuf[base] = sv;
        }
    }
    #pragma unroll
    for (int off = 1; off <= 32; off <<= 1) {
        s1 += __shfl_xor(s1, off, 64);
        s2 += __shfl_xor(s2, off, 64);
    }
    if (lane == 0) { red[wave] = s1; red[8 + wave] = s2; }
    __syncthreads();
    if (tid == 0) {
        float t1 = 0.f, t2 = 0.f;
        #pragma unroll
        for (int w = 0; w < 8; ++w) { t1 += red[w]; t2 += red[8 + w]; }
        atomicAdd(&stats[b * 2 + 0], t1);
        atomicAdd(&stats[b * 2 + 1], t2);
    }
}

// ---------------------------------------------------------------------------
// LN apply, vectorized 8 elems/thread
// ---------------------------------------------------------------------------
template <typename TO>
__global__ void ln_apply(const short* __restrict__ s, const float* __restrict__ stats,
                         TO* __restrict__ out, int perBatch) {
    const int bId = blockIdx.y;
    const size_t base = (size_t)bId * perBatch;
    const float n = (float)perBatch;
    const float mean = stats[bId * 2 + 0] / n;
    const float var  = stats[bId * 2 + 1] / n - mean * mean + 1e-5f;
    const float inv  = rsqrtf(var);
    const int stride = gridDim.x * 256 * 8;
    for (int i = (blockIdx.x * 256 + threadIdx.x) * 8; i < perBatch; i += stride) {
        const short8 v8 = *(const short8*)&s[base + i];
        float o[8];
        #pragma unroll
        for (int j = 0; j < 8; ++j) o[j] = (bs2f(v8[j]) - mean) * inv;
        if (sizeof(TO) == 4) {
            float4 f0 = {o[0], o[1], o[2], o[3]}, f1 = {o[4], o[5], o[6], o[7]};
            *(float4*)&((float*)out)[base + i] = f0;
            *(float4*)&((float*)out)[base + i + 4] = f1;
        } else {
            short8 r;
            #pragma unroll
            for (int j = 0; j < 8; ++j) r[j] = f2bs(o[j]);
            *(short8*)&((short*)out)[base + i] = r;
        }
    }
}

// ---------------------------------------------------------------------------
extern "C" void kernel_launch(void* const* d_in, const int* in_sizes, int n_in,
                              void* d_out, int out_size, void* d_ws, size_t ws_size,
                              hipStream_t stream) {
    const float* x  = (const float*)d_in[0];
    const float* wq = (const float*)d_in[1];
    const float* bq = (const float*)d_in[2];
    const float* wk = (const float*)d_in[3];
    const float* bk = (const float*)d_in[4];
    const float* wv = (const float*)d_in[5];
    const float* bv = (const float*)d_in[6];
    const float* w1 = (const float*)d_in[7];
    const float* b1 = (const float*)d_in[8];
    const float* w2 = (const float*)d_in[9];
    const float* b2 = (const float*)d_in[10];

    const int BL = CB * CL;
    const int perBatch = CL * CD;

    // ws layout, 48MB + 64B:
    //   [0,8):   weights: Wqkvt(6MB)+bqkv -> w1t -> w2t
    //   [8,16):  xbf (dead after QKV gemm)
    //   [16,32): qk [4096][2048] (dead after attn)
    //   [32,40): vT [2][1024][2048] (dead after attn)
    //   [8,40):  ff1 (reuse)
    //   [40,48): sbuf/hbuf
    //   [48MB):  stats
    char* ws = (char*)d_ws;
    const size_t MB = 1024 * 1024;
    short* Wqkvt = (short*)(ws);
    float* bqkv  = (float*)(ws + 6 * MB);
    short* w1t   = (short*)(ws);
    short* w2t   = (short*)(ws);
    short* xbf   = (short*)(ws + 8 * MB);
    short* qkb   = (short*)(ws + 16 * MB);
    short* vT    = (short*)(ws + 32 * MB);
    short* ff1   = (short*)(ws + 8 * MB);
    short* hbuf  = (short*)(ws + 40 * MB);
    float* stats = (float*)(ws + 48 * MB);

    dim3 blk(256);

    pack_bias_kernel<<<12, blk, 0, stream>>>(bq, bk, bv, bqkv, stats);
    cvt_x_kernel<<<BL * CD / 1024, blk, 0, stream>>>(x, xbf);
    transpose_qkv<<<dim3(32, 32, 3), blk, 0, stream>>>(wq, wk, wv, Wqkvt);

    // fused QKV: BN=192 (AI 76.8 vs 64, staged 402->327MB), W=8, grid
    // (16,32) = 512 blocks = 2 blocks/CU (proven-BW regime).
    gemm_mfma<192, 64, 0, 1, 8><<<dim3(3072 / 192, BL / 128), dim3(512), 0, stream>>>(
        xbf, Wqkvt, bqkv, qkb, vT, BL, 3072, CD, nullptr);

    // attention + residual + LN1 stats -> hbuf (s = x + attn)
    attn_mfma<<<dim3(CL / 128, NHEADS, CB), dim3(512), 0, stream>>>(qkb, vT, x, hbuf, stats);

    // LN1 apply in-place
    ln_apply<bf16><<<dim3(128, CB), blk, 0, stream>>>(hbuf, stats, (bf16*)hbuf, perBatch);

    // FFN1: BN=256 (AI 85), W=8, 2 blocks/CU (proven in R8)
    transpose_cvt<<<dim3(128, 32), blk, 0, stream>>>(w1, w1t, CD, CH, 0);
    gemm_mfma<256, 64, 1, 0, 8><<<dim3(CH / 256, BL / 128), dim3(512), 0, stream>>>(
        hbuf, w1t, b1, ff1, nullptr, BL, CH, CD, nullptr);

    // FFN2 + residual + LN2 stats (geometry-pinned best: BN=64, BK=128)
    transpose_cvt<<<dim3(32, 128), blk, 0, stream>>>(w2, w2t, CH, CD, 0);
    gemm_mfma<64, 128, 0, 2, 4><<<dim3(CD / 64, BL / 128), blk, 0, stream>>>(
        ff1, w2t, b2, hbuf, nullptr, BL, CD, CH, stats + 8);

    // LN2 apply -> out fp32
    ln_apply<float><<<dim3(128, CB), blk, 0, stream>>>(hbuf, stats + 8, (float*)d_out, perBatch);
}